// Round 13
// baseline (3854.916 us; speedup 1.0000x reference)
//
#include <hip/hip_runtime.h>
#include <math.h>

#define HDIM 512
#define TPB  512              // 8 waves, 1 element per thread
#define NW   8                // waves per block
#define MIW  4                // M-tiles per wave (32 tiles / 8 waves)
#define SSTR 516              // LDS dword row stride (2064 B, 16B aligned)
#define NCH  22               // 1 value + 8 grads + 13 hessian pairs
#define NPR  13
#define NRED 44               // 2 + 8 + 8 + 13 hess + 13 (g_a*g_b + h*hess) combined
#define LN_EPS 1e-5f

typedef _Float16 f16x8 __attribute__((ext_vector_type(8)));
typedef _Float16 f16x2 __attribute__((ext_vector_type(2)));
typedef float    f32x4 __attribute__((ext_vector_type(4)));
typedef unsigned int uint32;

// Needed Hessian pairs (a<=b, b>=4): 26 total, split 13/13 across passes.
template<int P> struct PairSet;
template<> struct PairSet<0> {
    static constexpr int A[NPR] = {0,1,2,3,4, 0,1,2,3,4,5, 0,1};
    static constexpr int B[NPR] = {4,4,4,4,4, 5,5,5,5,5,5, 6,6};
};
template<> struct PairSet<1> {
    static constexpr int A[NPR] = {2,3,4,5,6, 0,1,2,3,4,5,6,7};
    static constexpr int B[NPR] = {6,6,6,6,6, 7,7,7,7,7,7,7,7};
};

// ---------- DPP 4-stage row sum (VALU pipe). Lanes 15/31/47/63 hold their
// row-of-16 sums; cross-row combine happens in LDS (32 partials/term).
template<int CTRL>
__device__ __forceinline__ float dpp_add(float x) {
    int v = __builtin_amdgcn_update_dpp(0, __builtin_bit_cast(int, x),
                                        CTRL, 0xf, 0xf, true);
    return x + __builtin_bit_cast(float, v);
}
__device__ __forceinline__ float wave_sum4(float x) {
    x = dpp_add<0x111>(x);   // row_shr:1
    x = dpp_add<0x112>(x);   // row_shr:2
    x = dpp_add<0x114>(x);   // row_shr:4
    x = dpp_add<0x118>(x);   // row_shr:8 -> lane 15 (mod 16) = row sum
    return x;
}

// ---------- f32 -> hi/lo f16, pair-packed, DWORD-granular stores ----------
// Row layout: dwords [0..255] = [hi(2k)|hi(2k+1)], dwords [256..511] = [lo(2k)|lo(2k+1)].
// Even lane packs with odd neighbor (quad_perm 0xF5), one dword store per pair.
// Dword-granular (sub-dword LDS stores quarantined -- r9 tripwire).
__device__ __forceinline__ void store_hilo_pair(float v, float* rowbase, int tid) {
    const uint32 hiu = __builtin_bit_cast(uint32, __builtin_amdgcn_cvt_pkrtz(v, 0.f));
    const float  hf  = (float)__builtin_bit_cast(f16x2, hiu)[0];
    const uint32 lou = __builtin_bit_cast(uint32, __builtin_amdgcn_cvt_pkrtz((v - hf) * 1024.f, 0.f));
    const uint32 hin = (uint32)__builtin_amdgcn_update_dpp(0, (int)hiu, 0xF5, 0xf, 0xf, true);
    const uint32 lon = (uint32)__builtin_amdgcn_update_dpp(0, (int)lou, 0xF5, 0xf, 0xf, true);
    if ((tid & 1) == 0) {
        uint32* p = (uint32*)rowbase;
        const int d = tid >> 1;
        p[d]       = __builtin_amdgcn_perm(hin, hiu, 0x05040100u);  // [hi(e)|hi(e+1)]
        p[256 + d] = __builtin_amdgcn_perm(lon, lou, 0x05040100u);  // [lo(e)|lo(e+1)]
    }
}

// ---------- prep: W1,W2 f32 -> hi/lo f16 in MFMA-fragment-contiguous layout ----------
__global__ void prep_kernel(const float* __restrict__ W1, const float* __restrict__ W2,
                            _Float16* __restrict__ ws) {
    const int gid  = blockIdx.x * 256 + threadIdx.x;
    const int layer = gid >> 18;
    const int r     = gid & 262143;
    const int i = r >> 9, j = r & 511;
    const float v = (layer ? W2 : W1)[r];
    const _Float16 hi = (_Float16)v;
    const _Float16 lo = (_Float16)((v - (float)hi) * 1024.f);
    const int mt = i >> 4, m = i & 15, ks = j >> 5, q = (j >> 3) & 3, e = j & 7;
    const int off = (((mt * 16 + ks) * 4 + q) * 16 + m) * 8 + e;
    _Float16* base = ws + (size_t)layer * 524288;
    base[off] = hi;
    base[262144 + off] = lo;
}

// ---------- MFMA gemm: D[512, 22] = W * S, result staged back into S (ch-major) ----------
// Single fused K sweep, dual accumulators: D = accM + accC/1024.
// B fragments load DIRECTLY from pair-packed half-rows (16B aligned, zero perms).
// Round 13 single change: ks-loop unroll 1 -> 2 so iteration k+1's global
// A-loads (L2, ~200cy) issue under iteration k's MFMAs.
__device__ void gemm_mfma(float* __restrict__ S,
                          const _Float16* __restrict__ Whi,
                          const _Float16* __restrict__ Wlo,
                          int w, int lane)
{
    const int q = lane >> 4, m = lane & 15;
    const int ch0 = m;
    const int ch1 = (16 + m < NCH) ? (16 + m) : (NCH - 1);  // clamp garbage lanes
    f32x4 accM[MIW][2], accC[MIW][2];
    #pragma unroll
    for (int mi = 0; mi < MIW; ++mi) {
        accM[mi][0] = (f32x4){0.f, 0.f, 0.f, 0.f};
        accM[mi][1] = (f32x4){0.f, 0.f, 0.f, 0.f};
        accC[mi][0] = (f32x4){0.f, 0.f, 0.f, 0.f};
        accC[mi][1] = (f32x4){0.f, 0.f, 0.f, 0.f};
    }

    const float* rb0 = S + ch0 * SSTR;
    const float* rb1 = S + ch1 * SSTR;

    #pragma unroll 2
    for (int ks = 0; ks < 16; ++ks) {
        const int off = ks * 16 + q * 4;     // dword offset of 8 hi f16 (4 dwords)
        const f16x8 Bhi0 = *(const f16x8*)(rb0 + off);
        const f16x8 Blo0 = *(const f16x8*)(rb0 + 256 + off);
        const f16x8 Bhi1 = *(const f16x8*)(rb1 + off);
        const f16x8 Blo1 = *(const f16x8*)(rb1 + 256 + off);
        #pragma unroll
        for (int mi = 0; mi < MIW; ++mi) {
            const size_t fo = ((size_t)((w * MIW + mi) * 16 + ks) * 64 + lane) * 8;
            const f16x8 Ahi = *(const f16x8*)(Whi + fo);
            const f16x8 Alo = *(const f16x8*)(Wlo + fo);
            accM[mi][0] = __builtin_amdgcn_mfma_f32_16x16x32_f16(Ahi, Bhi0, accM[mi][0], 0, 0, 0);
            accC[mi][0] = __builtin_amdgcn_mfma_f32_16x16x32_f16(Ahi, Blo0, accC[mi][0], 0, 0, 0);
            accC[mi][0] = __builtin_amdgcn_mfma_f32_16x16x32_f16(Alo, Bhi0, accC[mi][0], 0, 0, 0);
            accM[mi][1] = __builtin_amdgcn_mfma_f32_16x16x32_f16(Ahi, Bhi1, accM[mi][1], 0, 0, 0);
            accC[mi][1] = __builtin_amdgcn_mfma_f32_16x16x32_f16(Ahi, Blo1, accC[mi][1], 0, 0, 0);
            accC[mi][1] = __builtin_amdgcn_mfma_f32_16x16x32_f16(Alo, Bhi1, accC[mi][1], 0, 0, 0);
        }
    }

    __syncthreads();   // all waves done reading S -> safe to overwrite with D (f32)
    #pragma unroll
    for (int mi = 0; mi < MIW; ++mi) {
        #pragma unroll
        for (int nt = 0; nt < 2; ++nt) {
            const int ch = nt * 16 + m;
            if (ch < NCH) {
                const f32x4 r = accM[mi][nt] + accC[mi][nt] * (1.f / 1024.f);
                const float4 st = {r[0], r[1], r[2], r[3]};
                *(float4*)(S + ch * SSTR + (w * MIW + mi) * 16 + q * 4) = st;
            }
        }
    }
    __syncthreads();
}

__device__ __forceinline__ void readback(float (&vals)[NCH],
                                         const float* __restrict__ b,
                                         const float* __restrict__ S, int tid)
{
    #pragma unroll
    for (int ch = 0; ch < NCH; ++ch) vals[ch] = S[ch * SSTR + tid];   // f32 D, stride-1
    vals[0] += b[tid];
}

// ---------- softplus chain + LN; writes S (pair-packed hi/lo) or final linear ----------
// fin layout: [0]=h [1]=h^2 [2..9]=g [10..17]=h*g [18..30]=hess
//             [31..43]=COMBINED g_a*g_b + h*hess  (vdd only ever uses the sum)
// Reductions: 4-stage DPP row sums, 32 partials/term, fixed-order combine.
template<int P, bool FINAL>
__device__ void ln_process(float (&vals)[NCH],
        const float* __restrict__ g, const float* __restrict__ be,
        float* __restrict__ S, float* __restrict__ red, float* __restrict__ fin,
        float* __restrict__ drv,
        float* __restrict__ sJ, float* __restrict__ sH,
        int tid, int lane, int w, float w3)
{
    const float pv  = vals[0];
    const float e   = expf(-fabsf(pv));
    const float sig = (pv >= 0.f) ? (1.f / (1.f + e)) : (e / (1.f + e));
    const float h   = fmaxf(pv, 0.f) + log1pf(e);
    const float spp = sig * (1.f - sig);
    #pragma unroll
    for (int t = 0; t < NPR; ++t) {
        const int a = PairSet<P>::A[t], b = PairSet<P>::B[t];
        vals[9+t] = sig * vals[9+t] + spp * vals[1+a] * vals[1+b];
    }
    #pragma unroll
    for (int a = 0; a < 8; ++a) vals[1+a] *= sig;
    vals[0] = h;

    const bool rstore = (lane & 15) == 15;
    const int  rbase  = (w * 4 + (lane >> 4)) * NRED;

    // --- reduction group 1: k = 0..21 (h, h^2, g, h*g, hess 0..3) ---
    {
        float pa[22];
        pa[0] = h;
        pa[1] = h * h;
        #pragma unroll
        for (int a = 0; a < 8; ++a) { pa[2+a] = vals[1+a]; pa[10+a] = h * vals[1+a]; }
        #pragma unroll
        for (int t = 0; t < 4; ++t) pa[18+t] = vals[9+t];
        #pragma unroll
        for (int k = 0; k < 22; ++k) pa[k] = wave_sum4(pa[k]);
        if (rstore) {
            #pragma unroll
            for (int k = 0; k < 22; ++k) red[rbase + k] = pa[k];
        }
    }
    // --- reduction group 2: k = 22..43 (hess 4..12, combined 0..12) ---
    {
        float pb[22];
        #pragma unroll
        for (int t = 0; t < 9; ++t) pb[t] = vals[9 + 4 + t];
        #pragma unroll
        for (int t = 0; t < NPR; ++t) {
            const int a = PairSet<P>::A[t], b = PairSet<P>::B[t];
            pb[9+t] = vals[1+a] * vals[1+b] + h * vals[9+t];
        }
        #pragma unroll
        for (int k = 0; k < 22; ++k) pb[k] = wave_sum4(pb[k]);
        if (rstore) {
            #pragma unroll
            for (int k = 0; k < 22; ++k) red[rbase + 22 + k] = pb[k];
        }
    }
    __syncthreads();
    if (tid < NRED) {
        float s0 = 0.f, s1 = 0.f, s2 = 0.f, s3 = 0.f;
        #pragma unroll
        for (int p = 0; p < 8; ++p) {
            s0 += red[(4*p + 0) * NRED + tid];
            s1 += red[(4*p + 1) * NRED + tid];
            s2 += red[(4*p + 2) * NRED + tid];
            s3 += red[(4*p + 3) * NRED + tid];
        }
        fin[tid] = (s0 + s1) + (s2 + s3);
    }
    __syncthreads();

    const float invH = 1.f / HDIM;
    // derived stats -> drv[] : [0]=mean [1]=rs [2..9]=mdot [10..17]=sdot [18..30]=mdd [31..43]=cy
    if (tid < 8) {
        const float mean = fin[0] * invH;
        const float var  = fin[1] * invH - mean * mean;
        const float rs   = rsqrtf(var + LN_EPS);
        if (tid == 0) { drv[0] = mean; drv[1] = rs; }
        const float md = fin[2+tid] * invH;
        drv[2+tid]  = md;
        drv[10+tid] = (fin[10+tid] * invH - mean * md) * rs;
    }
    __syncthreads();
    if (tid < NPR) {
        const float mean = drv[0], rs = drv[1];
        const int a = PairSet<P>::A[tid], b = PairSet<P>::B[tid];
        const float sda = drv[10+a], sdb = drv[10+b];
        const float mdd  = fin[18+tid] * invH;
        const float comb = fin[31+tid] * invH;            // (Sgg + Shh)/H
        const float vdd  = 2.f * (comb - drv[2+a] * drv[2+b] - mean * mdd);
        const float sdd  = (0.5f * vdd - sda * sdb) * rs;
        drv[18+tid] = mdd;
        drv[31+tid] = 2.f * sda * sdb * rs * rs - sdd * rs;
    }
    __syncthreads();

    const float mean = drv[0], rs = drv[1];

    if (!FINAL) {
        const int j = tid;
        const float gi = g[j], bi = be[j];
        const float y = (vals[0] - mean) * rs;
        store_hilo_pair(y * gi + bi, S, tid);
        float cd[8];
        #pragma unroll
        for (int a = 0; a < 8; ++a) {
            cd[a] = vals[1+a] - drv[2+a];
            store_hilo_pair((cd[a] - y * drv[10+a]) * rs * gi, S + (1+a) * SSTR, tid);
        }
        #pragma unroll
        for (int t = 0; t < NPR; ++t) {
            const int a = PairSet<P>::A[t], b = PairSet<P>::B[t];
            const float cdd = vals[9+t] - drv[18+t];
            const float ydd = cdd * rs - (cd[a]*drv[10+b] + cd[b]*drv[10+a]) * rs * rs
                              + y * drv[31+t];
            store_hilo_pair(ydd * gi, S + (9+t) * SSTR, tid);
        }
    } else {
        float pf[NCH];
        const int j = tid;
        const float gi = g[j], bi = be[j];
        const float y = (vals[0] - mean) * rs;
        pf[0] = w3 * (y * gi + bi);
        float cd[8];
        #pragma unroll
        for (int a = 0; a < 8; ++a) {
            cd[a] = vals[1+a] - drv[2+a];
            pf[1+a] = w3 * ((cd[a] - y * drv[10+a]) * rs * gi);
        }
        #pragma unroll
        for (int t = 0; t < NPR; ++t) {
            const int a = PairSet<P>::A[t], b = PairSet<P>::B[t];
            const float cdd = vals[9+t] - drv[18+t];
            const float ydd = cdd * rs - (cd[a]*drv[10+b] + cd[b]*drv[10+a]) * rs * rs
                              + y * drv[31+t];
            pf[9+t] = w3 * (ydd * gi);
        }
        #pragma unroll
        for (int k = 0; k < NCH; ++k) pf[k] = wave_sum4(pf[k]);
        if (rstore) {
            #pragma unroll
            for (int k = 0; k < NCH; ++k) red[rbase + k] = pf[k];
        }
        __syncthreads();
        if (tid < NCH) {
            float s0 = 0.f, s1 = 0.f, s2 = 0.f, s3 = 0.f;
            #pragma unroll
            for (int p = 0; p < 8; ++p) {
                s0 += red[(4*p + 0) * NRED + tid];
                s1 += red[(4*p + 1) * NRED + tid];
                s2 += red[(4*p + 2) * NRED + tid];
                s3 += red[(4*p + 3) * NRED + tid];
            }
            fin[tid] = (s0 + s1) + (s2 + s3);
        }
        __syncthreads();
        if (tid == 0) {
            if (P == 0) {
                #pragma unroll
                for (int a = 0; a < 8; ++a) sJ[a] = fin[1 + a];
            }
            #pragma unroll
            for (int t = 0; t < NPR; ++t) sH[P * NPR + t] = fin[9 + t];
        }
    }
}

template<int P>
__device__ void run_pass(int tid, int lane, int w, const float (&q)[8],
        const float* __restrict__ W0, const float* __restrict__ b0,
        const float* __restrict__ g0, const float* __restrict__ be0,
        const float* __restrict__ b1, const float* __restrict__ g1,
        const float* __restrict__ be1,
        const float* __restrict__ b2, const float* __restrict__ g2,
        const float* __restrict__ be2,
        const _Float16* __restrict__ Wf,
        float w3,
        float* S, float* red, float* fin, float* drv, float* sJ, float* sH)
{
    float vals[NCH];

    // ---- layer 0: q(8) -> 512 (no gemm); grads = W0 row, hess = 0
    {
        const float4 wa = *(const float4*)(W0 + tid * 8);
        const float4 wb = *(const float4*)(W0 + tid * 8 + 4);
        vals[0] = b0[tid]
            + wa.x*q[0] + wa.y*q[1] + wa.z*q[2] + wa.w*q[3]
            + wb.x*q[4] + wb.y*q[5] + wb.z*q[6] + wb.w*q[7];
        vals[1] = wa.x; vals[2] = wa.y; vals[3] = wa.z; vals[4] = wa.w;
        vals[5] = wb.x; vals[6] = wb.y; vals[7] = wb.z; vals[8] = wb.w;
        #pragma unroll
        for (int t = 0; t < NPR; ++t) vals[9+t] = 0.f;
    }
    ln_process<P, false>(vals, g0, be0, S, red, fin, drv, sJ, sH, tid, lane, w, w3);
    __syncthreads();

    // ---- layer 1
    gemm_mfma(S, Wf, Wf + 262144, w, lane);
    readback(vals, b1, S, tid);
    ln_process<P, false>(vals, g1, be1, S, red, fin, drv, sJ, sH, tid, lane, w, w3);
    __syncthreads();

    // ---- layer 2
    gemm_mfma(S, Wf + 524288, Wf + 786432, w, lane);
    readback(vals, b2, S, tid);
    ln_process<P, true>(vals, g2, be2, S, red, fin, drv, sJ, sH, tid, lane, w, w3);
    __syncthreads();
}

// Bisect discipline: r12-green + ks-loop unroll 2 ONLY (pure scheduling).
// Quarantined: red<->S aliasing (r5), sub-dword LDS stores (r9), >64KB LDS
// (r2/r3 -- suspected hipGraph-capture interaction), cross-pass reg stash (r8).
__global__ __launch_bounds__(TPB, 4)
void lnn_kernel(const float* __restrict__ x,
    const float* __restrict__ W0, const float* __restrict__ b0,
    const float* __restrict__ g0, const float* __restrict__ be0,
    const float* __restrict__ b1, const float* __restrict__ g1,
    const float* __restrict__ be1,
    const float* __restrict__ b2, const float* __restrict__ g2,
    const float* __restrict__ be2,
    const float* __restrict__ W3,
    const _Float16* __restrict__ Wf,
    float* __restrict__ out)
{
    __shared__ __align__(16) float S[NCH * SSTR];    // 45.4 KB: state / D-staging
    __shared__ __align__(16) float red[4 * NW * NRED];  // 5.5 KB: 32 partial rows
    __shared__ __align__(16) float fin[NRED + 4];
    __shared__ float drv[44];
    __shared__ float sJ[8];
    __shared__ float sH[26];

    const int tid  = threadIdx.x;
    const int lane = tid & 63;
    const int w    = tid >> 6;
    const long sample = blockIdx.x;

    float q[8];
    #pragma unroll
    for (int a = 0; a < 8; ++a) q[a] = x[sample * 8 + a];
    const float w3 = W3[tid];

    run_pass<0>(tid, lane, w, q, W0, b0, g0, be0, b1, g1, be1, b2, g2, be2,
                Wf, w3, S, red, fin, drv, sJ, sH);
    run_pass<1>(tid, lane, w, q, W0, b0, g0, be0, b1, g1, be1, b2, g2, be2,
                Wf, w3, S, red, fin, drv, sJ, sH);

    if (tid == 0) {
        const int off[4] = {0, 5, 11, 18};
        double Hd[26];
        for (int t = 0; t < 26; ++t) Hd[t] = (double)sH[t];
        double r[4];
        for (int k = 0; k < 4; ++k) {
            double s = (double)sJ[k];
            for (int j = 0; j < 4; ++j) s -= Hd[off[k] + j] * (double)q[4 + j];
            r[k] = s;
        }
        double A[4][5];
        for (int jj = 0; jj < 4; ++jj) {
            for (int k = 0; k < 4; ++k) {
                const int lo = (jj < k ? jj : k) + 4;
                const int hi = (jj < k ? k : jj) + 4;
                A[jj][k] = Hd[off[hi - 4] + lo];
            }
            A[jj][4] = r[jj];
        }
        for (int c = 0; c < 4; ++c) {
            int pr = c; double mx = fabs(A[c][c]);
            for (int rr = c + 1; rr < 4; ++rr)
                if (fabs(A[rr][c]) > mx) { mx = fabs(A[rr][c]); pr = rr; }
            if (pr != c)
                for (int cc = c; cc < 5; ++cc) {
                    double t = A[c][cc]; A[c][cc] = A[pr][cc]; A[pr][cc] = t;
                }
            const double pinv = 1.0 / A[c][c];
            for (int rr = 0; rr < 4; ++rr) if (rr != c) {
                const double f = A[rr][c] * pinv;
                for (int cc = c; cc < 5; ++cc) A[rr][cc] -= f * A[c][cc];
            }
        }
        #pragma unroll
        for (int k = 0; k < 4; ++k)
            out[sample * 4 + k] = (float)(A[k][4] / A[k][k]);
    }
}

extern "C" void kernel_launch(void* const* d_in, const int* in_sizes, int n_in,
                              void* d_out, int out_size, void* d_ws, size_t ws_size,
                              hipStream_t stream) {
    const float* x   = (const float*)d_in[0];
    const float* W0  = (const float*)d_in[1];
    const float* b0  = (const float*)d_in[2];
    const float* g0  = (const float*)d_in[3];
    const float* be0 = (const float*)d_in[4];
    const float* W1  = (const float*)d_in[5];
    const float* b1  = (const float*)d_in[6];
    const float* g1  = (const float*)d_in[7];
    const float* be1 = (const float*)d_in[8];
    const float* W2  = (const float*)d_in[9];
    const float* b2  = (const float*)d_in[10];
    const float* g2  = (const float*)d_in[11];
    const float* be2 = (const float*)d_in[12];
    const float* W3  = (const float*)d_in[13];
    float* out = (float*)d_out;

    _Float16* Wf = (_Float16*)d_ws;   // 2 MB: [W1hi|W1lo|W2hi|W2lo] fragment layout
    const int B = in_sizes[0] / 8;    // 16384

    hipLaunchKernelGGL(prep_kernel, dim3(2048), dim3(256), 0, stream, W1, W2, Wf);
    hipLaunchKernelGGL(lnn_kernel, dim3(B), dim3(TPB), 0, stream,
                       x, W0, b0, g0, be0, b1, g1, be1, b2, g2, be2, W3, Wf, out);
}

// Round 14
// 3740.436 us; speedup vs baseline: 1.0306x; 1.0306x over previous
//
#include <hip/hip_runtime.h>
#include <math.h>

#define HDIM 512
#define TPB  512              // 8 waves, 1 element per thread
#define NW   8                // waves per block
#define MIW  4                // M-tiles per wave (32 tiles / 8 waves)
#define SSTR 516              // LDS dword row stride (2064 B, 16B aligned)
#define NCH  22               // 1 value + 8 grads + 13 hessian pairs
#define NPR  13
#define NRED 44               // 2 + 8 + 8 + 13 hess + 13 (g_a*g_b + h*hess) combined
#define LN_EPS 1e-5f

typedef _Float16 f16x8 __attribute__((ext_vector_type(8)));
typedef _Float16 f16x2 __attribute__((ext_vector_type(2)));
typedef float    f32x4 __attribute__((ext_vector_type(4)));
typedef unsigned int uint32;

// Needed Hessian pairs (a<=b, b>=4): 26 total, split 13/13 across passes.
template<int P> struct PairSet;
template<> struct PairSet<0> {
    static constexpr int A[NPR] = {0,1,2,3,4, 0,1,2,3,4,5, 0,1};
    static constexpr int B[NPR] = {4,4,4,4,4, 5,5,5,5,5,5, 6,6};
};
template<> struct PairSet<1> {
    static constexpr int A[NPR] = {2,3,4,5,6, 0,1,2,3,4,5,6,7};
    static constexpr int B[NPR] = {6,6,6,6,6, 7,7,7,7,7,7,7,7};
};

// ---------- DPP 4-stage row sum (VALU pipe). Lanes 15/31/47/63 hold their
// row-of-16 sums; cross-row combine happens in LDS (32 partials/term).
template<int CTRL>
__device__ __forceinline__ float dpp_add(float x) {
    int v = __builtin_amdgcn_update_dpp(0, __builtin_bit_cast(int, x),
                                        CTRL, 0xf, 0xf, true);
    return x + __builtin_bit_cast(float, v);
}
__device__ __forceinline__ float wave_sum4(float x) {
    x = dpp_add<0x111>(x);   // row_shr:1
    x = dpp_add<0x112>(x);   // row_shr:2
    x = dpp_add<0x114>(x);   // row_shr:4
    x = dpp_add<0x118>(x);   // row_shr:8 -> lane 15 (mod 16) = row sum
    return x;
}

// ---------- f32 -> hi/lo f16, pair-packed, DWORD-granular stores ----------
// Row layout: dwords [0..255] = [hi(2k)|hi(2k+1)], dwords [256..511] = [lo(2k)|lo(2k+1)].
// Even lane packs with odd neighbor (quad_perm 0xF5), one dword store per pair.
// Dword-granular (sub-dword LDS stores quarantined -- r9 tripwire).
__device__ __forceinline__ void store_hilo_pair(float v, float* rowbase, int tid) {
    const uint32 hiu = __builtin_bit_cast(uint32, __builtin_amdgcn_cvt_pkrtz(v, 0.f));
    const float  hf  = (float)__builtin_bit_cast(f16x2, hiu)[0];
    const uint32 lou = __builtin_bit_cast(uint32, __builtin_amdgcn_cvt_pkrtz((v - hf) * 1024.f, 0.f));
    const uint32 hin = (uint32)__builtin_amdgcn_update_dpp(0, (int)hiu, 0xF5, 0xf, 0xf, true);
    const uint32 lon = (uint32)__builtin_amdgcn_update_dpp(0, (int)lou, 0xF5, 0xf, 0xf, true);
    if ((tid & 1) == 0) {
        uint32* p = (uint32*)rowbase;
        const int d = tid >> 1;
        p[d]       = __builtin_amdgcn_perm(hin, hiu, 0x05040100u);  // [hi(e)|hi(e+1)]
        p[256 + d] = __builtin_amdgcn_perm(lon, lou, 0x05040100u);  // [lo(e)|lo(e+1)]
    }
}

// ---------- prep: W1,W2 f32 -> hi/lo f16 in MFMA-fragment-contiguous layout ----------
__global__ void prep_kernel(const float* __restrict__ W1, const float* __restrict__ W2,
                            _Float16* __restrict__ ws) {
    const int gid  = blockIdx.x * 256 + threadIdx.x;
    const int layer = gid >> 18;
    const int r     = gid & 262143;
    const int i = r >> 9, j = r & 511;
    const float v = (layer ? W2 : W1)[r];
    const _Float16 hi = (_Float16)v;
    const _Float16 lo = (_Float16)((v - (float)hi) * 1024.f);
    const int mt = i >> 4, m = i & 15, ks = j >> 5, q = (j >> 3) & 3, e = j & 7;
    const int off = (((mt * 16 + ks) * 4 + q) * 16 + m) * 8 + e;
    _Float16* base = ws + (size_t)layer * 524288;
    base[off] = hi;
    base[262144 + off] = lo;
}

// ---------- MFMA gemm: D[512, 22] = W * S, result staged back into S (ch-major) ----------
// Single fused K sweep, dual accumulators: D = accM + accC/1024.
// B fragments load DIRECTLY from pair-packed half-rows (16B aligned, zero perms).
// unroll 1 restored: unroll 2 spilled (r13 canary -- WRITE_SIZE 2.1e4 -> 1.85e5 KB).
__device__ void gemm_mfma(float* __restrict__ S,
                          const _Float16* __restrict__ Whi,
                          const _Float16* __restrict__ Wlo,
                          int w, int lane)
{
    const int q = lane >> 4, m = lane & 15;
    const int ch0 = m;
    const int ch1 = (16 + m < NCH) ? (16 + m) : (NCH - 1);  // clamp garbage lanes
    f32x4 accM[MIW][2], accC[MIW][2];
    #pragma unroll
    for (int mi = 0; mi < MIW; ++mi) {
        accM[mi][0] = (f32x4){0.f, 0.f, 0.f, 0.f};
        accM[mi][1] = (f32x4){0.f, 0.f, 0.f, 0.f};
        accC[mi][0] = (f32x4){0.f, 0.f, 0.f, 0.f};
        accC[mi][1] = (f32x4){0.f, 0.f, 0.f, 0.f};
    }

    const float* rb0 = S + ch0 * SSTR;
    const float* rb1 = S + ch1 * SSTR;

    #pragma unroll 1
    for (int ks = 0; ks < 16; ++ks) {
        const int off = ks * 16 + q * 4;     // dword offset of 8 hi f16 (4 dwords)
        const f16x8 Bhi0 = *(const f16x8*)(rb0 + off);
        const f16x8 Blo0 = *(const f16x8*)(rb0 + 256 + off);
        const f16x8 Bhi1 = *(const f16x8*)(rb1 + off);
        const f16x8 Blo1 = *(const f16x8*)(rb1 + 256 + off);
        #pragma unroll
        for (int mi = 0; mi < MIW; ++mi) {
            const size_t fo = ((size_t)((w * MIW + mi) * 16 + ks) * 64 + lane) * 8;
            const f16x8 Ahi = *(const f16x8*)(Whi + fo);
            const f16x8 Alo = *(const f16x8*)(Wlo + fo);
            accM[mi][0] = __builtin_amdgcn_mfma_f32_16x16x32_f16(Ahi, Bhi0, accM[mi][0], 0, 0, 0);
            accC[mi][0] = __builtin_amdgcn_mfma_f32_16x16x32_f16(Ahi, Blo0, accC[mi][0], 0, 0, 0);
            accC[mi][0] = __builtin_amdgcn_mfma_f32_16x16x32_f16(Alo, Bhi0, accC[mi][0], 0, 0, 0);
            accM[mi][1] = __builtin_amdgcn_mfma_f32_16x16x32_f16(Ahi, Bhi1, accM[mi][1], 0, 0, 0);
            accC[mi][1] = __builtin_amdgcn_mfma_f32_16x16x32_f16(Ahi, Blo1, accC[mi][1], 0, 0, 0);
            accC[mi][1] = __builtin_amdgcn_mfma_f32_16x16x32_f16(Alo, Bhi1, accC[mi][1], 0, 0, 0);
        }
    }

    __syncthreads();   // all waves done reading S -> safe to overwrite with D (f32)
    #pragma unroll
    for (int mi = 0; mi < MIW; ++mi) {
        #pragma unroll
        for (int nt = 0; nt < 2; ++nt) {
            const int ch = nt * 16 + m;
            if (ch < NCH) {
                const f32x4 r = accM[mi][nt] + accC[mi][nt] * (1.f / 1024.f);
                const float4 st = {r[0], r[1], r[2], r[3]};
                *(float4*)(S + ch * SSTR + (w * MIW + mi) * 16 + q * 4) = st;
            }
        }
    }
    __syncthreads();
}

__device__ __forceinline__ void readback(float (&vals)[NCH],
                                         const float* __restrict__ b,
                                         const float* __restrict__ S, int tid)
{
    #pragma unroll
    for (int ch = 0; ch < NCH; ++ch) vals[ch] = S[ch * SSTR + tid];   // f32 D, stride-1
    vals[0] += b[tid];
}

// ---------- softplus chain + LN; writes S (pair-packed hi/lo) or final linear ----------
// fin layout: [0]=h [1]=h^2 [2..9]=g [10..17]=h*g [18..30]=hess
//             [31..43]=COMBINED g_a*g_b + h*hess  (vdd only ever uses the sum)
// Round 14: expf/log1pf -> __expf/__logf(1+e) (HW v_exp/v_log paths).
// log1p->log(1+e) abs error <= ~1e-7 (e<=1, no cancellation regime).
template<int P, bool FINAL>
__device__ void ln_process(float (&vals)[NCH],
        const float* __restrict__ g, const float* __restrict__ be,
        float* __restrict__ S, float* __restrict__ red, float* __restrict__ fin,
        float* __restrict__ drv,
        float* __restrict__ sJ, float* __restrict__ sH,
        int tid, int lane, int w, float w3)
{
    const float pv  = vals[0];
    const float e   = __expf(-fabsf(pv));
    const float sig = (pv >= 0.f) ? (1.f / (1.f + e)) : (e / (1.f + e));
    const float h   = fmaxf(pv, 0.f) + __logf(1.f + e);
    const float spp = sig * (1.f - sig);
    #pragma unroll
    for (int t = 0; t < NPR; ++t) {
        const int a = PairSet<P>::A[t], b = PairSet<P>::B[t];
        vals[9+t] = sig * vals[9+t] + spp * vals[1+a] * vals[1+b];
    }
    #pragma unroll
    for (int a = 0; a < 8; ++a) vals[1+a] *= sig;
    vals[0] = h;

    const bool rstore = (lane & 15) == 15;
    const int  rbase  = (w * 4 + (lane >> 4)) * NRED;

    // --- reduction group 1: k = 0..21 (h, h^2, g, h*g, hess 0..3) ---
    {
        float pa[22];
        pa[0] = h;
        pa[1] = h * h;
        #pragma unroll
        for (int a = 0; a < 8; ++a) { pa[2+a] = vals[1+a]; pa[10+a] = h * vals[1+a]; }
        #pragma unroll
        for (int t = 0; t < 4; ++t) pa[18+t] = vals[9+t];
        #pragma unroll
        for (int k = 0; k < 22; ++k) pa[k] = wave_sum4(pa[k]);
        if (rstore) {
            #pragma unroll
            for (int k = 0; k < 22; ++k) red[rbase + k] = pa[k];
        }
    }
    // --- reduction group 2: k = 22..43 (hess 4..12, combined 0..12) ---
    {
        float pb[22];
        #pragma unroll
        for (int t = 0; t < 9; ++t) pb[t] = vals[9 + 4 + t];
        #pragma unroll
        for (int t = 0; t < NPR; ++t) {
            const int a = PairSet<P>::A[t], b = PairSet<P>::B[t];
            pb[9+t] = vals[1+a] * vals[1+b] + h * vals[9+t];
        }
        #pragma unroll
        for (int k = 0; k < 22; ++k) pb[k] = wave_sum4(pb[k]);
        if (rstore) {
            #pragma unroll
            for (int k = 0; k < 22; ++k) red[rbase + 22 + k] = pb[k];
        }
    }
    __syncthreads();
    if (tid < NRED) {
        float s0 = 0.f, s1 = 0.f, s2 = 0.f, s3 = 0.f;
        #pragma unroll
        for (int p = 0; p < 8; ++p) {
            s0 += red[(4*p + 0) * NRED + tid];
            s1 += red[(4*p + 1) * NRED + tid];
            s2 += red[(4*p + 2) * NRED + tid];
            s3 += red[(4*p + 3) * NRED + tid];
        }
        fin[tid] = (s0 + s1) + (s2 + s3);
    }
    __syncthreads();

    const float invH = 1.f / HDIM;
    // derived stats -> drv[] : [0]=mean [1]=rs [2..9]=mdot [10..17]=sdot [18..30]=mdd [31..43]=cy
    if (tid < 8) {
        const float mean = fin[0] * invH;
        const float var  = fin[1] * invH - mean * mean;
        const float rs   = rsqrtf(var + LN_EPS);
        if (tid == 0) { drv[0] = mean; drv[1] = rs; }
        const float md = fin[2+tid] * invH;
        drv[2+tid]  = md;
        drv[10+tid] = (fin[10+tid] * invH - mean * md) * rs;
    }
    __syncthreads();
    if (tid < NPR) {
        const float mean = drv[0], rs = drv[1];
        const int a = PairSet<P>::A[tid], b = PairSet<P>::B[tid];
        const float sda = drv[10+a], sdb = drv[10+b];
        const float mdd  = fin[18+tid] * invH;
        const float comb = fin[31+tid] * invH;            // (Sgg + Shh)/H
        const float vdd  = 2.f * (comb - drv[2+a] * drv[2+b] - mean * mdd);
        const float sdd  = (0.5f * vdd - sda * sdb) * rs;
        drv[18+tid] = mdd;
        drv[31+tid] = 2.f * sda * sdb * rs * rs - sdd * rs;
    }
    __syncthreads();

    const float mean = drv[0], rs = drv[1];

    if (!FINAL) {
        const int j = tid;
        const float gi = g[j], bi = be[j];
        const float y = (vals[0] - mean) * rs;
        store_hilo_pair(y * gi + bi, S, tid);
        float cd[8];
        #pragma unroll
        for (int a = 0; a < 8; ++a) {
            cd[a] = vals[1+a] - drv[2+a];
            store_hilo_pair((cd[a] - y * drv[10+a]) * rs * gi, S + (1+a) * SSTR, tid);
        }
        #pragma unroll
        for (int t = 0; t < NPR; ++t) {
            const int a = PairSet<P>::A[t], b = PairSet<P>::B[t];
            const float cdd = vals[9+t] - drv[18+t];
            const float ydd = cdd * rs - (cd[a]*drv[10+b] + cd[b]*drv[10+a]) * rs * rs
                              + y * drv[31+t];
            store_hilo_pair(ydd * gi, S + (9+t) * SSTR, tid);
        }
    } else {
        float pf[NCH];
        const int j = tid;
        const float gi = g[j], bi = be[j];
        const float y = (vals[0] - mean) * rs;
        pf[0] = w3 * (y * gi + bi);
        float cd[8];
        #pragma unroll
        for (int a = 0; a < 8; ++a) {
            cd[a] = vals[1+a] - drv[2+a];
            pf[1+a] = w3 * ((cd[a] - y * drv[10+a]) * rs * gi);
        }
        #pragma unroll
        for (int t = 0; t < NPR; ++t) {
            const int a = PairSet<P>::A[t], b = PairSet<P>::B[t];
            const float cdd = vals[9+t] - drv[18+t];
            const float ydd = cdd * rs - (cd[a]*drv[10+b] + cd[b]*drv[10+a]) * rs * rs
                              + y * drv[31+t];
            pf[9+t] = w3 * (ydd * gi);
        }
        #pragma unroll
        for (int k = 0; k < NCH; ++k) pf[k] = wave_sum4(pf[k]);
        if (rstore) {
            #pragma unroll
            for (int k = 0; k < NCH; ++k) red[rbase + k] = pf[k];
        }
        __syncthreads();
        if (tid < NCH) {
            float s0 = 0.f, s1 = 0.f, s2 = 0.f, s3 = 0.f;
            #pragma unroll
            for (int p = 0; p < 8; ++p) {
                s0 += red[(4*p + 0) * NRED + tid];
                s1 += red[(4*p + 1) * NRED + tid];
                s2 += red[(4*p + 2) * NRED + tid];
                s3 += red[(4*p + 3) * NRED + tid];
            }
            fin[tid] = (s0 + s1) + (s2 + s3);
        }
        __syncthreads();
        if (tid == 0) {
            if (P == 0) {
                #pragma unroll
                for (int a = 0; a < 8; ++a) sJ[a] = fin[1 + a];
            }
            #pragma unroll
            for (int t = 0; t < NPR; ++t) sH[P * NPR + t] = fin[9 + t];
        }
    }
}

template<int P>
__device__ void run_pass(int tid, int lane, int w, const float (&q)[8],
        const float* __restrict__ W0, const float* __restrict__ b0,
        const float* __restrict__ g0, const float* __restrict__ be0,
        const float* __restrict__ b1, const float* __restrict__ g1,
        const float* __restrict__ be1,
        const float* __restrict__ b2, const float* __restrict__ g2,
        const float* __restrict__ be2,
        const _Float16* __restrict__ Wf,
        float w3,
        float* S, float* red, float* fin, float* drv, float* sJ, float* sH)
{
    float vals[NCH];

    // ---- layer 0: q(8) -> 512 (no gemm); grads = W0 row, hess = 0
    {
        const float4 wa = *(const float4*)(W0 + tid * 8);
        const float4 wb = *(const float4*)(W0 + tid * 8 + 4);
        vals[0] = b0[tid]
            + wa.x*q[0] + wa.y*q[1] + wa.z*q[2] + wa.w*q[3]
            + wb.x*q[4] + wb.y*q[5] + wb.z*q[6] + wb.w*q[7];
        vals[1] = wa.x; vals[2] = wa.y; vals[3] = wa.z; vals[4] = wa.w;
        vals[5] = wb.x; vals[6] = wb.y; vals[7] = wb.z; vals[8] = wb.w;
        #pragma unroll
        for (int t = 0; t < NPR; ++t) vals[9+t] = 0.f;
    }
    ln_process<P, false>(vals, g0, be0, S, red, fin, drv, sJ, sH, tid, lane, w, w3);
    __syncthreads();

    // ---- layer 1
    gemm_mfma(S, Wf, Wf + 262144, w, lane);
    readback(vals, b1, S, tid);
    ln_process<P, false>(vals, g1, be1, S, red, fin, drv, sJ, sH, tid, lane, w, w3);
    __syncthreads();

    // ---- layer 2
    gemm_mfma(S, Wf + 524288, Wf + 786432, w, lane);
    readback(vals, b2, S, tid);
    ln_process<P, true>(vals, g2, be2, S, red, fin, drv, sJ, sH, tid, lane, w, w3);
    __syncthreads();
}

// Bisect discipline: r12-green + HW transcendentals (__expf/__logf) ONLY;
// unroll-2 reverted (r13 spill canary). Quarantined: red<->S aliasing (r5),
// sub-dword LDS stores (r9), >64KB LDS (r2/r3), cross-pass reg stash (r8),
// gemm ks-loop unroll>=2 (r13 spills).
__global__ __launch_bounds__(TPB, 4)
void lnn_kernel(const float* __restrict__ x,
    const float* __restrict__ W0, const float* __restrict__ b0,
    const float* __restrict__ g0, const float* __restrict__ be0,
    const float* __restrict__ b1, const float* __restrict__ g1,
    const float* __restrict__ be1,
    const float* __restrict__ b2, const float* __restrict__ g2,
    const float* __restrict__ be2,
    const float* __restrict__ W3,
    const _Float16* __restrict__ Wf,
    float* __restrict__ out)
{
    __shared__ __align__(16) float S[NCH * SSTR];    // 45.4 KB: state / D-staging
    __shared__ __align__(16) float red[4 * NW * NRED];  // 5.5 KB: 32 partial rows
    __shared__ __align__(16) float fin[NRED + 4];
    __shared__ float drv[44];
    __shared__ float sJ[8];
    __shared__ float sH[26];

    const int tid  = threadIdx.x;
    const int lane = tid & 63;
    const int w    = tid >> 6;
    const long sample = blockIdx.x;

    float q[8];
    #pragma unroll
    for (int a = 0; a < 8; ++a) q[a] = x[sample * 8 + a];
    const float w3 = W3[tid];

    run_pass<0>(tid, lane, w, q, W0, b0, g0, be0, b1, g1, be1, b2, g2, be2,
                Wf, w3, S, red, fin, drv, sJ, sH);
    run_pass<1>(tid, lane, w, q, W0, b0, g0, be0, b1, g1, be1, b2, g2, be2,
                Wf, w3, S, red, fin, drv, sJ, sH);

    if (tid == 0) {
        const int off[4] = {0, 5, 11, 18};
        double Hd[26];
        for (int t = 0; t < 26; ++t) Hd[t] = (double)sH[t];
        double r[4];
        for (int k = 0; k < 4; ++k) {
            double s = (double)sJ[k];
            for (int j = 0; j < 4; ++j) s -= Hd[off[k] + j] * (double)q[4 + j];
            r[k] = s;
        }
        double A[4][5];
        for (int jj = 0; jj < 4; ++jj) {
            for (int k = 0; k < 4; ++k) {
                const int lo = (jj < k ? jj : k) + 4;
                const int hi = (jj < k ? k : jj) + 4;
                A[jj][k] = Hd[off[hi - 4] + lo];
            }
            A[jj][4] = r[jj];
        }
        for (int c = 0; c < 4; ++c) {
            int pr = c; double mx = fabs(A[c][c]);
            for (int rr = c + 1; rr < 4; ++rr)
                if (fabs(A[rr][c]) > mx) { mx = fabs(A[rr][c]); pr = rr; }
            if (pr != c)
                for (int cc = c; cc < 5; ++cc) {
                    double t = A[c][cc]; A[c][cc] = A[pr][cc]; A[pr][cc] = t;
                }
            const double pinv = 1.0 / A[c][c];
            for (int rr = 0; rr < 4; ++rr) if (rr != c) {
                const double f = A[rr][c] * pinv;
                for (int cc = c; cc < 5; ++cc) A[rr][cc] -= f * A[c][cc];
            }
        }
        #pragma unroll
        for (int k = 0; k < 4; ++k)
            out[sample * 4 + k] = (float)(A[k][4] / A[k][k]);
    }
}

extern "C" void kernel_launch(void* const* d_in, const int* in_sizes, int n_in,
                              void* d_out, int out_size, void* d_ws, size_t ws_size,
                              hipStream_t stream) {
    const float* x   = (const float*)d_in[0];
    const float* W0  = (const float*)d_in[1];
    const float* b0  = (const float*)d_in[2];
    const float* g0  = (const float*)d_in[3];
    const float* be0 = (const float*)d_in[4];
    const float* W1  = (const float*)d_in[5];
    const float* b1  = (const float*)d_in[6];
    const float* g1  = (const float*)d_in[7];
    const float* be1 = (const float*)d_in[8];
    const float* W2  = (const float*)d_in[9];
    const float* b2  = (const float*)d_in[10];
    const float* g2  = (const float*)d_in[11];
    const float* be2 = (const float*)d_in[12];
    const float* W3  = (const float*)d_in[13];
    float* out = (float*)d_out;

    _Float16* Wf = (_Float16*)d_ws;   // 2 MB: [W1hi|W1lo|W2hi|W2lo] fragment layout
    const int B = in_sizes[0] / 8;    // 16384

    hipLaunchKernelGGL(prep_kernel, dim3(2048), dim3(256), 0, stream, W1, W2, Wf);
    hipLaunchKernelGGL(lnn_kernel, dim3(B), dim3(TPB), 0, stream,
                       x, W0, b0, g0, be0, b1, g1, be1, b2, g2, be2, W3, Wf, out);
}